// Round 1
// baseline (70.409 us; speedup 1.0000x reference)
//
#include <hip/hip_runtime.h>

// L1 pairwise distance: out[i][j] = sum_d |x1[i][d] - x2[j][d]|
// x1: [N1, 64] f32, x2: [N2, 64] f32, out: [N1, N2] f32.
// The reference's mean-adjustment cancels algebraically: (x1-adj)-(x2-adj) = x1-x2.
// clamp_min(0) is a no-op on a sum of |.|.

#define TILE 64
#define PAD  68   // 64 + 4 floats pad: rows stay 16B-aligned, bank stride 4 -> <=2-way (free)
#define D_FIXED 64

__global__ __launch_bounds__(256, 4)
void l1dist_kernel(const float* __restrict__ x1, const float* __restrict__ x2,
                   float* __restrict__ out, int N1, int N2) {
    __shared__ float s1[TILE * PAD];
    __shared__ float s2[TILE * PAD];

    const int bi = blockIdx.y;   // x1 row-tile
    const int bj = blockIdx.x;   // x2 row-tile (output column-tile)
    const int tx = threadIdx.x;  // 0..15
    const int ty = threadIdx.y;  // 0..15
    const int t  = ty * 16 + tx; // 0..255

    // ---- stage both 64x64 f32 tiles into LDS (coalesced float4 loads) ----
    const float* g1 = x1 + (size_t)bi * TILE * D_FIXED;
    const float* g2 = x2 + (size_t)bj * TILE * D_FIXED;
    #pragma unroll
    for (int f = 0; f < 4; ++f) {
        int idx = t + f * 256;          // float4 index 0..1023
        int row = idx >> 4;             // 0..63
        int c4  = (idx & 15) << 2;      // 0,4,...,60
        float4 v1 = *(const float4*)(g1 + row * D_FIXED + c4);
        float4 v2 = *(const float4*)(g2 + row * D_FIXED + c4);
        *(float4*)(s1 + row * PAD + c4) = v1;
        *(float4*)(s2 + row * PAD + c4) = v2;
    }
    __syncthreads();

    // ---- each thread: 4x4 output tile, rows i = ty+16r, cols j = tx+16r ----
    float acc[4][4];
    #pragma unroll
    for (int i = 0; i < 4; ++i)
        #pragma unroll
        for (int j = 0; j < 4; ++j) acc[i][j] = 0.0f;

    #pragma unroll
    for (int d = 0; d < D_FIXED; d += 4) {
        float4 a[4], b[4];
        #pragma unroll
        for (int r = 0; r < 4; ++r)
            a[r] = *(const float4*)(s1 + (ty + 16 * r) * PAD + d);
        #pragma unroll
        for (int r = 0; r < 4; ++r)
            b[r] = *(const float4*)(s2 + (tx + 16 * r) * PAD + d);

        #pragma unroll
        for (int i = 0; i < 4; ++i) {
            #pragma unroll
            for (int j = 0; j < 4; ++j) {
                float d0 = a[i].x - b[j].x;
                float d1 = a[i].y - b[j].y;
                float d2 = a[i].z - b[j].z;
                float d3 = a[i].w - b[j].w;
                // fabsf folds into v_add_f32 input modifiers:
                // t01 = |d0|+|d1|; t23 = |d2|+|d3|; acc += t01; acc += t23 -> 4 adds
                acc[i][j] += (fabsf(d0) + fabsf(d1)) + (fabsf(d2) + fabsf(d3));
            }
        }
    }

    // ---- store: lanes (ty 0..3 within wave) x (tx 0..15) -> 4x 64B segments ----
    const int i0 = bi * TILE;
    const int j0 = bj * TILE;
    #pragma unroll
    for (int ri = 0; ri < 4; ++ri) {
        int i = i0 + ty + 16 * ri;
        #pragma unroll
        for (int rj = 0; rj < 4; ++rj) {
            int j = j0 + tx + 16 * rj;
            out[(size_t)i * N2 + j] = acc[ri][rj];
        }
    }
}

extern "C" void kernel_launch(void* const* d_in, const int* in_sizes, int n_in,
                              void* d_out, int out_size, void* d_ws, size_t ws_size,
                              hipStream_t stream) {
    const float* x1 = (const float*)d_in[0];
    const float* x2 = (const float*)d_in[1];
    float* out = (float*)d_out;

    const int N1 = in_sizes[0] / D_FIXED;  // 2048
    const int N2 = in_sizes[1] / D_FIXED;  // 2048

    dim3 block(16, 16);
    dim3 grid(N2 / TILE, N1 / TILE);       // (32, 32)
    l1dist_kernel<<<grid, block, 0, stream>>>(x1, x2, out, N1, N2);
}